// Round 9
// baseline (65.522 us; speedup 1.0000x reference)
//
#include <hip/hip_runtime.h>

// GAT layer, N=8192, IN_F=512, OUT_F=64, alpha=0.2
// exp(lrelu(s1_i+s2_j)) factors on each side of s2_j <= thr_i = -s1_i =>
// row_i = [A_i*Sum_{s2>thr} exp(s2)Wh + B_i*Sum_{s2<=thr} exp(.2 s2)Wh] / (scalars)
// TWO plain kernels (grid-sync ~28us measured; node slot ~13.5us => 2 nodes min):
//   k1: Wh = h@W^T, s1, s2
//   k2: per-block PRIVATE bucket-sort of s2 (erff-spread buckets, ids in LDS,
//       s2 values held in VGPRs through the sort), chunk sums + LDS scans for
//       a 16-feature slice, exact compares in the threshold's bucket.
// LDS dieted to ~69KB -> 2 blocks/CU (R8 was 100KB -> 1 block/CU, latency-bound).

constexpr int NV  = 8192;
constexpr int FIN = 512;
constexpr int NT  = 512;
constexpr int CH  = 32;      // positions per chunk
constexpr int NCH = 256;     // NV/CH
constexpr int NBK = 4096;    // value buckets

// ================= k1: Wh = h @ W^T ; s1 ; s2 =============================
__global__ __launch_bounds__(NT, 4) void k1_gemm(
    const float* __restrict__ h, const float* __restrict__ W,
    const float* __restrict__ a, float* __restrict__ Wh,
    float* __restrict__ s1, float* __restrict__ s2g)
{
    __shared__ float smem[8192];   // 32 KB W-chunk
    const int t = threadIdx.x, b = blockIdx.x;
    const int lane = t & 63, w = t >> 6;
    const int row0 = __builtin_amdgcn_readfirstlane(b * 16 + w * 2);
    float4 A0 = {0.f,0.f,0.f,0.f}, A1 = {0.f,0.f,0.f,0.f};
    const float4* Wf4 = reinterpret_cast<const float4*>(W);
    float4* S4 = reinterpret_cast<float4*>(smem);
    for (int pass = 0; pass < 4; ++pass) {
        // stage W[:, pass*128 .. +128) into LDS, rotation-swizzled
        #pragma unroll
        for (int it = 0; it < 4; ++it) {
            const int g = it * 512 + t;          // 0..2047
            const int f = g >> 5, kk4 = g & 31;
            S4[kk4 * 64 + ((f + kk4) & 63)] = Wf4[f * 128 + pass * 32 + kk4];
        }
        __syncthreads();
        const float* hb = h + (size_t)row0 * FIN + pass * 128;
        #pragma unroll 8
        for (int k4 = 0; k4 < 32; ++k4) {
            const float4 wv = S4[k4 * 64 + ((lane + k4) & 63)];
            const float4 h0 = *reinterpret_cast<const float4*>(hb + k4 * 4);
            const float4 h1 = *reinterpret_cast<const float4*>(hb + FIN + k4 * 4);
            A0.x = fmaf(h0.x, wv.x, A0.x); A0.y = fmaf(h0.y, wv.y, A0.y);
            A0.z = fmaf(h0.z, wv.z, A0.z); A0.w = fmaf(h0.w, wv.w, A0.w);
            A1.x = fmaf(h1.x, wv.x, A1.x); A1.y = fmaf(h1.y, wv.y, A1.y);
            A1.z = fmaf(h1.z, wv.z, A1.z); A1.w = fmaf(h1.w, wv.w, A1.w);
        }
        __syncthreads();
    }
    const float acc0 = (A0.x + A0.y) + (A0.z + A0.w);
    const float acc1 = (A1.x + A1.y) + (A1.z + A1.w);
    Wh[(size_t)row0 * 64 + lane] = acc0;
    Wh[(size_t)(row0 + 1) * 64 + lane] = acc1;
    const float a1 = a[lane], a2 = a[64 + lane];
    float r0s1 = acc0 * a1, r0s2 = acc0 * a2;
    float r1s1 = acc1 * a1, r1s2 = acc1 * a2;
    #pragma unroll
    for (int off = 32; off > 0; off >>= 1) {
        r0s1 += __shfl_xor(r0s1, off);
        r0s2 += __shfl_xor(r0s2, off);
        r1s1 += __shfl_xor(r1s1, off);
        r1s2 += __shfl_xor(r1s2, off);
    }
    if (lane == 0) {
        s1[row0] = r0s1;     s2g[row0] = r0s2;
        s1[row0 + 1] = r1s1; s2g[row0 + 1] = r1s2;
    }
}

// monotone spreading map: Gaussian s2 -> ~uniform bucket index
__device__ __forceinline__ int bucketOf(float x, float mu, float is) {
    const float c = erff((x - mu) * is * 0.70710678f);   // in [-1,1]
    const int b = (int)((c * 0.5f + 0.5f) * 4096.0f);
    return min(max(b, 0), NBK - 1);
}

// ================= k2: private bucket-sort + slice output ==================
// block b: fq = b&3 -> features [fq*16,+16); rg = b>>2 -> rows [rg*128,+128)
__global__ __launch_bounds__(NT, 4) void k2_out(
    const float* __restrict__ Wh, const float* __restrict__ s1,
    const float* __restrict__ s2g, float* __restrict__ out)
{
    __shared__ unsigned       Bst[NBK];          // 16 KB
    __shared__ unsigned short sid[NV];           // 16 KB
    __shared__ float Us[257 * 16];               // 16.45 KB
    __shared__ float Vp[257 * 16];               // 16.45 KB
    __shared__ float sus[257];
    __shared__ float svp[257];
    __shared__ float segTU[256], segTV[256], segSU[16], segSV[16];
    __shared__ float fscr[16];
    __shared__ unsigned uscr[8];

    const int t = threadIdx.x, b = blockIdx.x;
    const int lane = t & 63, w = t >> 6;
    const int fq = b & 3;
    const int rg = b >> 2;

    // ---- load this thread's 16 s2 values into VGPRs + moments ----
    float xr[16];
    float S = 0.f, SQ = 0.f;
    #pragma unroll
    for (int q = 0; q < 4; ++q) {
        const float4 v = *reinterpret_cast<const float4*>(s2g + q * 2048 + t * 4);
        xr[q * 4 + 0] = v.x; xr[q * 4 + 1] = v.y;
        xr[q * 4 + 2] = v.z; xr[q * 4 + 3] = v.w;
        S += (v.x + v.y) + (v.z + v.w);
        SQ += (v.x*v.x + v.y*v.y) + (v.z*v.z + v.w*v.w);
    }
    #pragma unroll
    for (int off = 32; off > 0; off >>= 1) {
        S  += __shfl_xor(S, off);
        SQ += __shfl_xor(SQ, off);
    }
    if (lane == 0) { fscr[w] = S; fscr[8 + w] = SQ; }
    // zero histogram while the reduce lands
    #pragma unroll
    for (int e = 0; e < 8; ++e) Bst[t * 8 + e] = 0u;
    __syncthreads();
    float Stot = 0.f, SQtot = 0.f;
    #pragma unroll
    for (int q = 0; q < 8; ++q) { Stot += fscr[q]; SQtot += fscr[8 + q]; }
    const float mu = Stot * (1.f / NV);
    const float var = fmaxf(SQtot * (1.f / NV) - mu * mu, 1e-30f);
    const float isg = rsqrtf(var);

    // ---- histogram (buckets from registers) ----
    #pragma unroll
    for (int q = 0; q < 16; ++q)
        atomicAdd(&Bst[bucketOf(xr[q], mu, isg)], 1u);
    __syncthreads();

    // ---- exclusive scan of 4096 counts (8/thread + block scan) ----
    {
        unsigned cnt[8]; unsigned tt = 0u;
        #pragma unroll
        for (int e = 0; e < 8; ++e) { cnt[e] = Bst[t * 8 + e]; tt += cnt[e]; }
        unsigned x = tt;
        #pragma unroll
        for (int d = 1; d < 64; d <<= 1) {
            const unsigned y = __shfl_up(x, d);
            if (lane >= d) x += y;
        }
        if (lane == 63) uscr[w] = x;
        __syncthreads();
        unsigned wb = 0u;
        for (int q = 0; q < 8; ++q) if (q < w) wb += uscr[q];
        unsigned run = wb + x - tt;    // exclusive base
        #pragma unroll
        for (int e = 0; e < 8; ++e) { const unsigned c = cnt[e]; Bst[t * 8 + e] = run; run += c; }
    }
    __syncthreads();

    // ---- scatter: sid = ids in bucket order; Bst[b] becomes end-of-bucket ----
    #pragma unroll
    for (int q = 0; q < 4; ++q) {
        #pragma unroll
        for (int e = 0; e < 4; ++e) {
            const int j = q * 2048 + t * 4 + e;
            const unsigned slot = atomicAdd(&Bst[bucketOf(xr[q * 4 + e], mu, isg)], 1u);
            sid[slot] = (unsigned short)j;
        }
    }
    __syncthreads();

    // ---- chunk sums: unit = (chunk c, 4-feat group fs); 2 units/thread ----
    #pragma unroll
    for (int rep = 0; rep < 2; ++rep) {
        const int unit = rep * NT + t;
        const int c = unit >> 2;
        const int fs = (unit & 3) * 4;
        float au[4] = {0.f,0.f,0.f,0.f}, av[4] = {0.f,0.f,0.f,0.f};
        float su = 0.f, sv = 0.f;
        for (int q = 0; q < CH; ++q) {
            const int p = c * CH + q;
            const int j = sid[p];
            const float x = s2g[j];                       // L2 hit
            const float u = __expf(x);
            const float v = __expf(0.2f * x);
            const float4 wv = *reinterpret_cast<const float4*>(
                                  Wh + (size_t)j * 64 + fq * 16 + fs);
            au[0]=fmaf(u,wv.x,au[0]); au[1]=fmaf(u,wv.y,au[1]);
            au[2]=fmaf(u,wv.z,au[2]); au[3]=fmaf(u,wv.w,au[3]);
            av[0]=fmaf(v,wv.x,av[0]); av[1]=fmaf(v,wv.y,av[1]);
            av[2]=fmaf(v,wv.z,av[2]); av[3]=fmaf(v,wv.w,av[3]);
            su += u; sv += v;
        }
        *reinterpret_cast<float4*>(Us + c * 16 + fs) = make_float4(au[0],au[1],au[2],au[3]);
        *reinterpret_cast<float4*>(Vp + c * 16 + fs) = make_float4(av[0],av[1],av[2],av[3]);
        if ((unit & 3) == 0) { sus[c] = su; svp[c] = sv; }
    }
    __syncthreads();

    // ---- level-1 scans: 16 feats x 16 segs of 16 chunks (+ scalar lane) ----
    if (t < 256) {
        const int f = t & 15, seg = t >> 4;
        float run = 0.f;
        for (int q = 15; q >= 0; --q) {
            const int c = seg * 16 + q;
            run += Us[c * 16 + f];
            Us[c * 16 + f] = run;
        }
        segTU[seg * 16 + f] = run;
        float rv = 0.f;
        for (int q = 0; q < 16; ++q) {
            const int c = seg * 16 + q;
            const float tmp = Vp[c * 16 + f];
            Vp[c * 16 + f] = rv;
            rv += tmp;
        }
        segTV[seg * 16 + f] = rv;
    } else if (t < 272) {
        const int sg = t - 256;
        float r = 0.f;
        for (int q = 15; q >= 0; --q) { const int c = sg * 16 + q; r += sus[c]; sus[c] = r; }
        segSU[sg] = r;
        float rv = 0.f;
        for (int q = 0; q < 16; ++q) { const int c = sg * 16 + q; const float tmp = svp[c]; svp[c] = rv; rv += tmp; }
        segSV[sg] = rv;
    }
    __syncthreads();

    // ---- level-2 offsets + boundary entries ----
    if (t < 256) {
        const int f = t & 15, seg = t >> 4;
        float offU = 0.f, offV = 0.f;
        for (int s = seg + 1; s < 16; ++s) offU += segTU[s * 16 + f];
        for (int s = 0; s < seg; ++s)      offV += segTV[s * 16 + f];
        for (int q = 0; q < 16; ++q) {
            const int c = seg * 16 + q;
            Us[c * 16 + f] += offU;
            Vp[c * 16 + f] += offV;
        }
    } else if (t < 272) {
        const int sg = t - 256;
        float oU = 0.f, oV = 0.f;
        for (int s = sg + 1; s < 16; ++s) oU += segSU[s];
        for (int s = 0; s < sg; ++s)      oV += segSV[s];
        for (int q = 0; q < 16; ++q) { sus[sg * 16 + q] += oU; svp[sg * 16 + q] += oV; }
    } else if (t < 288) {
        const int f = t - 272;
        Us[256 * 16 + f] = 0.f;
        float tot = 0.f;
        for (int s = 0; s < 16; ++s) tot += segTV[s * 16 + f];
        Vp[256 * 16 + f] = tot;
    } else if (t == 288) {
        float tv = 0.f;
        for (int s = 0; s < 16; ++s) tv += segSV[s];
        sus[256] = 0.f;
        svp[256] = tv;
    }
    __syncthreads();

    // ---- outputs: thread -> (row r, 4-feat group fs) ----
    const int r = t >> 2, fs = (t & 3) * 4;
    const int i = rg * 128 + r;
    const float s1v = s1[i];
    const float thr = -s1v;
    const int bt = bucketOf(thr, mu, isg);
    const unsigned K0 = bt ? Bst[bt - 1] : 0u;     // start of thr's bucket
    const unsigned K1 = Bst[bt];                   // end of thr's bucket
    const int c0   = (int)(K0 >> 5);
    const int cEnd = (int)((K1 + 31u) >> 5);
    float accU[4] = {0.f,0.f,0.f,0.f}, accV[4] = {0.f,0.f,0.f,0.f};
    float sau = 0.f, sav = 0.f;
    for (int p = c0 * CH; p < cEnd * CH; ++p) {
        const int j = sid[p];
        const float x = s2g[j];
        const float4 wv = *reinterpret_cast<const float4*>(
                              Wh + (size_t)j * 64 + fq * 16 + fs);
        const bool isV = ((unsigned)p < K0) | (((unsigned)p < K1) & (x <= thr));
        if (isV) {
            const float v = __expf(0.2f * x);
            accV[0]=fmaf(v,wv.x,accV[0]); accV[1]=fmaf(v,wv.y,accV[1]);
            accV[2]=fmaf(v,wv.z,accV[2]); accV[3]=fmaf(v,wv.w,accV[3]);
            sav += v;
        } else {
            const float u = __expf(x);
            accU[0]=fmaf(u,wv.x,accU[0]); accU[1]=fmaf(u,wv.y,accU[1]);
            accU[2]=fmaf(u,wv.z,accU[2]); accU[3]=fmaf(u,wv.w,accU[3]);
            sau += u;
        }
    }
    const float A  = __expf(s1v);
    const float Bc = __expf(0.2f * s1v);
    const float den = A * (sus[cEnd] + sau) + Bc * (svp[c0] + sav);
    const float inv = 1.f / den;
    float4 o;
    o.x = (A * (Us[cEnd*16 + fs+0] + accU[0]) + Bc * (Vp[c0*16 + fs+0] + accV[0])) * inv;
    o.y = (A * (Us[cEnd*16 + fs+1] + accU[1]) + Bc * (Vp[c0*16 + fs+1] + accV[1])) * inv;
    o.z = (A * (Us[cEnd*16 + fs+2] + accU[2]) + Bc * (Vp[c0*16 + fs+2] + accV[2])) * inv;
    o.w = (A * (Us[cEnd*16 + fs+3] + accU[3]) + Bc * (Vp[c0*16 + fs+3] + accV[3])) * inv;
    *reinterpret_cast<float4*>(out + (size_t)i * 64 + fq * 16 + fs) = o;
}

// ----------------------------------------------------------------
extern "C" void kernel_launch(void* const* d_in, const int* in_sizes, int n_in,
                              void* d_out, int out_size, void* d_ws, size_t ws_size,
                              hipStream_t stream) {
    (void)in_sizes; (void)n_in; (void)out_size; (void)ws_size;
    const float* h = (const float*)d_in[0];
    // d_in[1] = adj : unused by the reference computation
    const float* W = (const float*)d_in[2];
    const float* a = (const float*)d_in[3];
    float* out = (float*)d_out;

    float* Wh  = (float*)d_ws;                 // 8192*64
    float* s1  = Wh + (size_t)NV * 64;         // 8192
    float* s2g = s1 + NV;                      // 8192

    hipLaunchKernelGGL(k1_gemm, dim3(512), dim3(NT), 0, stream,
                       h, W, a, Wh, s1, s2g);
    hipLaunchKernelGGL(k2_out, dim3(256), dim3(NT), 0, stream,
                       Wh, s1, s2g, out);
}

// Round 10
// 51.059 us; speedup vs baseline: 1.2832x; 1.2832x over previous
//
#include <hip/hip_runtime.h>

// GAT layer, N=8192, IN_F=512, OUT_F=64, alpha=0.2
// exp(lrelu(s1_i+s2_j)) factors on each side of s2_j <= thr_i = -s1_i =>
// row_i = [A_i*Sum_{s2>thr} exp(s2)Wh + B_i*Sum_{s2<=thr} exp(.2 s2)Wh] / (scalars)
// TWO plain kernels (grid-sync ~28us measured thrice; node slot ~13.5us):
//   k1: Wh = h@W^T, s1, s2
//   k2: per-block PRIVATE bucket-sort of s2 (values ride in VGPRs to the
//       scatter, which emits sid+sval in sorted order -> ALL hot-loop value
//       reads are contiguous LDS), chunk sums + LDS scans for a 16-feature
//       slice, exact compares in the threshold's bucket.
// R9 lesson: L2 4B-gathers in the hot loops cost more than 2x TLP gains.
// This round: LDS-resident values AND 4 waves/SIMD via 1024-thread blocks.

constexpr int NV  = 8192;
constexpr int FIN = 512;
constexpr int NT  = 512;      // k1 threads/block
constexpr int NT2 = 1024;     // k2 threads/block (16 waves, 1 block/CU)
constexpr int CH  = 32;       // positions per chunk
constexpr int NCH = 256;      // NV/CH
constexpr int NBK = 4096;     // value buckets

// ================= k1: Wh = h @ W^T ; s1 ; s2 =============================
__global__ __launch_bounds__(NT, 4) void k1_gemm(
    const float* __restrict__ h, const float* __restrict__ W,
    const float* __restrict__ a, float* __restrict__ Wh,
    float* __restrict__ s1, float* __restrict__ s2g)
{
    __shared__ float smem[8192];   // 32 KB W-chunk
    const int t = threadIdx.x, b = blockIdx.x;
    const int lane = t & 63, w = t >> 6;
    const int row0 = __builtin_amdgcn_readfirstlane(b * 16 + w * 2);
    float4 A0 = {0.f,0.f,0.f,0.f}, A1 = {0.f,0.f,0.f,0.f};
    const float4* Wf4 = reinterpret_cast<const float4*>(W);
    float4* S4 = reinterpret_cast<float4*>(smem);
    for (int pass = 0; pass < 4; ++pass) {
        // stage W[:, pass*128 .. +128) into LDS, rotation-swizzled
        #pragma unroll
        for (int it = 0; it < 4; ++it) {
            const int g = it * 512 + t;          // 0..2047
            const int f = g >> 5, kk4 = g & 31;
            S4[kk4 * 64 + ((f + kk4) & 63)] = Wf4[f * 128 + pass * 32 + kk4];
        }
        __syncthreads();
        const float* hb = h + (size_t)row0 * FIN + pass * 128;
        #pragma unroll 8
        for (int k4 = 0; k4 < 32; ++k4) {
            const float4 wv = S4[k4 * 64 + ((lane + k4) & 63)];
            const float4 h0 = *reinterpret_cast<const float4*>(hb + k4 * 4);
            const float4 h1 = *reinterpret_cast<const float4*>(hb + FIN + k4 * 4);
            A0.x = fmaf(h0.x, wv.x, A0.x); A0.y = fmaf(h0.y, wv.y, A0.y);
            A0.z = fmaf(h0.z, wv.z, A0.z); A0.w = fmaf(h0.w, wv.w, A0.w);
            A1.x = fmaf(h1.x, wv.x, A1.x); A1.y = fmaf(h1.y, wv.y, A1.y);
            A1.z = fmaf(h1.z, wv.z, A1.z); A1.w = fmaf(h1.w, wv.w, A1.w);
        }
        __syncthreads();
    }
    const float acc0 = (A0.x + A0.y) + (A0.z + A0.w);
    const float acc1 = (A1.x + A1.y) + (A1.z + A1.w);
    Wh[(size_t)row0 * 64 + lane] = acc0;
    Wh[(size_t)(row0 + 1) * 64 + lane] = acc1;
    const float a1 = a[lane], a2 = a[64 + lane];
    float r0s1 = acc0 * a1, r0s2 = acc0 * a2;
    float r1s1 = acc1 * a1, r1s2 = acc1 * a2;
    #pragma unroll
    for (int off = 32; off > 0; off >>= 1) {
        r0s1 += __shfl_xor(r0s1, off);
        r0s2 += __shfl_xor(r0s2, off);
        r1s1 += __shfl_xor(r1s1, off);
        r1s2 += __shfl_xor(r1s2, off);
    }
    if (lane == 0) {
        s1[row0] = r0s1;     s2g[row0] = r0s2;
        s1[row0 + 1] = r1s1; s2g[row0 + 1] = r1s2;
    }
}

// monotone spreading map: Gaussian s2 -> ~uniform bucket index
__device__ __forceinline__ int bucketOf(float x, float mu, float is) {
    const float c = erff((x - mu) * is * 0.70710678f);   // in [-1,1]
    const int b = (int)((c * 0.5f + 0.5f) * 4096.0f);
    return min(max(b, 0), NBK - 1);
}

// ================= k2: private bucket-sort + slice output ==================
// block b: fq = b&3 -> features [fq*16,+16); rg = b>>2 -> rows [rg*128,+128)
__global__ __launch_bounds__(NT2, 2) void k2_out(
    const float* __restrict__ Wh, const float* __restrict__ s1,
    const float* __restrict__ s2g, float* __restrict__ out)
{
    __shared__ unsigned       Bst[NBK];          // 16 KB
    __shared__ unsigned short sid[NV];           // 16 KB   ids in sorted order
    __shared__ float          sval[NV];          // 32 KB   s2 in sorted order
    __shared__ float Us[257 * 16];               // 16.45 KB
    __shared__ float Vp[257 * 16];               // 16.45 KB
    __shared__ float sus[257];
    __shared__ float svp[257];
    __shared__ float segTU[256], segTV[256], segSU[16], segSV[16];
    __shared__ float fscr[32];
    __shared__ unsigned uscr[16];

    const int t = threadIdx.x, b = blockIdx.x;
    const int lane = t & 63, w = t >> 6;     // w in [0,16)
    const int fq = b & 3;
    const int rg = b >> 2;

    // ---- load this thread's 8 s2 values into VGPRs + moments ----
    float xr[8];
    float S = 0.f, SQ = 0.f;
    #pragma unroll
    for (int q = 0; q < 2; ++q) {
        const float4 v = *reinterpret_cast<const float4*>(s2g + q * 4096 + t * 4);
        xr[q * 4 + 0] = v.x; xr[q * 4 + 1] = v.y;
        xr[q * 4 + 2] = v.z; xr[q * 4 + 3] = v.w;
        S += (v.x + v.y) + (v.z + v.w);
        SQ += (v.x*v.x + v.y*v.y) + (v.z*v.z + v.w*v.w);
    }
    #pragma unroll
    for (int off = 32; off > 0; off >>= 1) {
        S  += __shfl_xor(S, off);
        SQ += __shfl_xor(SQ, off);
    }
    if (lane == 0) { fscr[w] = S; fscr[16 + w] = SQ; }
    // zero histogram while the reduce lands
    #pragma unroll
    for (int e = 0; e < 4; ++e) Bst[t * 4 + e] = 0u;
    __syncthreads();
    float Stot = 0.f, SQtot = 0.f;
    #pragma unroll
    for (int q = 0; q < 16; ++q) { Stot += fscr[q]; SQtot += fscr[16 + q]; }
    const float mu = Stot * (1.f / NV);
    const float var = fmaxf(SQtot * (1.f / NV) - mu * mu, 1e-30f);
    const float isg = rsqrtf(var);

    // ---- histogram (buckets from registers) ----
    #pragma unroll
    for (int q = 0; q < 8; ++q)
        atomicAdd(&Bst[bucketOf(xr[q], mu, isg)], 1u);
    __syncthreads();

    // ---- exclusive scan of 4096 counts (4/thread + block scan) ----
    {
        unsigned cnt[4]; unsigned tt = 0u;
        #pragma unroll
        for (int e = 0; e < 4; ++e) { cnt[e] = Bst[t * 4 + e]; tt += cnt[e]; }
        unsigned x = tt;
        #pragma unroll
        for (int d = 1; d < 64; d <<= 1) {
            const unsigned y = __shfl_up(x, d);
            if (lane >= d) x += y;
        }
        if (lane == 63) uscr[w] = x;
        __syncthreads();
        unsigned wb = 0u;
        #pragma unroll
        for (int q = 0; q < 16; ++q) if (q < w) wb += uscr[q];
        unsigned run = wb + x - tt;    // exclusive base
        #pragma unroll
        for (int e = 0; e < 4; ++e) { const unsigned c = cnt[e]; Bst[t * 4 + e] = run; run += c; }
    }
    __syncthreads();

    // ---- scatter ids + values; Bst[b] becomes end-of-bucket ----
    #pragma unroll
    for (int q = 0; q < 2; ++q) {
        #pragma unroll
        for (int e = 0; e < 4; ++e) {
            const int j = q * 4096 + t * 4 + e;
            const float x = xr[q * 4 + e];
            const unsigned slot = atomicAdd(&Bst[bucketOf(x, mu, isg)], 1u);
            sid[slot] = (unsigned short)j;
            sval[slot] = x;
        }
    }
    __syncthreads();

    // ---- chunk sums: unit = (chunk c, 4-feat group fs); 1 unit/thread ----
    {
        const int c = t >> 2;
        const int fs = (t & 3) * 4;
        float au[4] = {0.f,0.f,0.f,0.f}, av[4] = {0.f,0.f,0.f,0.f};
        float su = 0.f, sv = 0.f;
        #pragma unroll 4
        for (int q = 0; q < CH; ++q) {
            const int p = c * CH + q;
            const int j = sid[p];
            const float x = sval[p];                 // contiguous LDS
            const float u = __expf(x);
            const float v = __expf(0.2f * x);
            const float4 wv = *reinterpret_cast<const float4*>(
                                  Wh + (size_t)j * 64 + fq * 16 + fs);
            au[0]=fmaf(u,wv.x,au[0]); au[1]=fmaf(u,wv.y,au[1]);
            au[2]=fmaf(u,wv.z,au[2]); au[3]=fmaf(u,wv.w,au[3]);
            av[0]=fmaf(v,wv.x,av[0]); av[1]=fmaf(v,wv.y,av[1]);
            av[2]=fmaf(v,wv.z,av[2]); av[3]=fmaf(v,wv.w,av[3]);
            su += u; sv += v;
        }
        *reinterpret_cast<float4*>(Us + c * 16 + fs) = make_float4(au[0],au[1],au[2],au[3]);
        *reinterpret_cast<float4*>(Vp + c * 16 + fs) = make_float4(av[0],av[1],av[2],av[3]);
        if ((t & 3) == 0) { sus[c] = su; svp[c] = sv; }
    }
    __syncthreads();

    // ---- level-1 scans: 16 feats x 16 segs of 16 chunks (+ scalar lane) ----
    if (t < 256) {
        const int f = t & 15, seg = t >> 4;
        float run = 0.f;
        for (int q = 15; q >= 0; --q) {
            const int c = seg * 16 + q;
            run += Us[c * 16 + f];
            Us[c * 16 + f] = run;
        }
        segTU[seg * 16 + f] = run;
        float rv = 0.f;
        for (int q = 0; q < 16; ++q) {
            const int c = seg * 16 + q;
            const float tmp = Vp[c * 16 + f];
            Vp[c * 16 + f] = rv;
            rv += tmp;
        }
        segTV[seg * 16 + f] = rv;
    } else if (t < 272) {
        const int sg = t - 256;
        float r = 0.f;
        for (int q = 15; q >= 0; --q) { const int c = sg * 16 + q; r += sus[c]; sus[c] = r; }
        segSU[sg] = r;
        float rv = 0.f;
        for (int q = 0; q < 16; ++q) { const int c = sg * 16 + q; const float tmp = svp[c]; svp[c] = rv; rv += tmp; }
        segSV[sg] = rv;
    }
    __syncthreads();

    // ---- level-2 offsets + boundary entries ----
    if (t < 256) {
        const int f = t & 15, seg = t >> 4;
        float offU = 0.f, offV = 0.f;
        for (int s = seg + 1; s < 16; ++s) offU += segTU[s * 16 + f];
        for (int s = 0; s < seg; ++s)      offV += segTV[s * 16 + f];
        for (int q = 0; q < 16; ++q) {
            const int c = seg * 16 + q;
            Us[c * 16 + f] += offU;
            Vp[c * 16 + f] += offV;
        }
    } else if (t < 272) {
        const int sg = t - 256;
        float oU = 0.f, oV = 0.f;
        for (int s = sg + 1; s < 16; ++s) oU += segSU[s];
        for (int s = 0; s < sg; ++s)      oV += segSV[s];
        for (int q = 0; q < 16; ++q) { sus[sg * 16 + q] += oU; svp[sg * 16 + q] += oV; }
    } else if (t < 288) {
        const int f = t - 272;
        Us[256 * 16 + f] = 0.f;
        float tot = 0.f;
        for (int s = 0; s < 16; ++s) tot += segTV[s * 16 + f];
        Vp[256 * 16 + f] = tot;
    } else if (t == 288) {
        float tv = 0.f;
        for (int s = 0; s < 16; ++s) tv += segSV[s];
        sus[256] = 0.f;
        svp[256] = tv;
    }
    __syncthreads();

    // ---- outputs: thread t<512 -> (row r, 4-feat group fs) ----
    if (t < 512) {
        const int r = t >> 2, fs = (t & 3) * 4;
        const int i = rg * 128 + r;
        const float s1v = s1[i];
        const float thr = -s1v;
        const int bt = bucketOf(thr, mu, isg);
        const unsigned K0 = bt ? Bst[bt - 1] : 0u;     // start of thr's bucket
        const unsigned K1 = Bst[bt];                   // end of thr's bucket
        const int c0   = (int)(K0 >> 5);
        const int cEnd = (int)((K1 + 31u) >> 5);
        float accU[4] = {0.f,0.f,0.f,0.f}, accV[4] = {0.f,0.f,0.f,0.f};
        float sau = 0.f, sav = 0.f;
        for (int p = c0 * CH; p < cEnd * CH; ++p) {
            const int j = sid[p];
            const float x = sval[p];
            const float4 wv = *reinterpret_cast<const float4*>(
                                  Wh + (size_t)j * 64 + fq * 16 + fs);
            const bool isV = ((unsigned)p < K0) | (((unsigned)p < K1) & (x <= thr));
            if (isV) {
                const float v = __expf(0.2f * x);
                accV[0]=fmaf(v,wv.x,accV[0]); accV[1]=fmaf(v,wv.y,accV[1]);
                accV[2]=fmaf(v,wv.z,accV[2]); accV[3]=fmaf(v,wv.w,accV[3]);
                sav += v;
            } else {
                const float u = __expf(x);
                accU[0]=fmaf(u,wv.x,accU[0]); accU[1]=fmaf(u,wv.y,accU[1]);
                accU[2]=fmaf(u,wv.z,accU[2]); accU[3]=fmaf(u,wv.w,accU[3]);
                sau += u;
            }
        }
        const float A  = __expf(s1v);
        const float Bc = __expf(0.2f * s1v);
        const float den = A * (sus[cEnd] + sau) + Bc * (svp[c0] + sav);
        const float inv = 1.f / den;
        float4 o;
        o.x = (A * (Us[cEnd*16 + fs+0] + accU[0]) + Bc * (Vp[c0*16 + fs+0] + accV[0])) * inv;
        o.y = (A * (Us[cEnd*16 + fs+1] + accU[1]) + Bc * (Vp[c0*16 + fs+1] + accV[1])) * inv;
        o.z = (A * (Us[cEnd*16 + fs+2] + accU[2]) + Bc * (Vp[c0*16 + fs+2] + accV[2])) * inv;
        o.w = (A * (Us[cEnd*16 + fs+3] + accU[3]) + Bc * (Vp[c0*16 + fs+3] + accV[3])) * inv;
        *reinterpret_cast<float4*>(out + (size_t)i * 64 + fq * 16 + fs) = o;
    }
}

// ----------------------------------------------------------------
extern "C" void kernel_launch(void* const* d_in, const int* in_sizes, int n_in,
                              void* d_out, int out_size, void* d_ws, size_t ws_size,
                              hipStream_t stream) {
    (void)in_sizes; (void)n_in; (void)out_size; (void)ws_size;
    const float* h = (const float*)d_in[0];
    // d_in[1] = adj : unused by the reference computation
    const float* W = (const float*)d_in[2];
    const float* a = (const float*)d_in[3];
    float* out = (float*)d_out;

    float* Wh  = (float*)d_ws;                 // 8192*64
    float* s1  = Wh + (size_t)NV * 64;         // 8192
    float* s2g = s1 + NV;                      // 8192

    hipLaunchKernelGGL(k1_gemm, dim3(512), dim3(NT), 0, stream,
                       h, W, a, Wh, s1, s2g);
    hipLaunchKernelGGL(k2_out, dim3(256), dim3(NT2), 0, stream,
                       Wh, s1, s2g, out);
}